// Round 3
// baseline (448.503 us; speedup 1.0000x reference)
//
#include <hip/hip_runtime.h>
#include <hip/hip_bf16.h>

#define DD 768
#define HH 3072
#define BB 64
#define TT 262   // NCLS + P tokens per batch

typedef __bf16 bf16x8 __attribute__((ext_vector_type(8)));
typedef float f32x4 __attribute__((ext_vector_type(4)));
typedef unsigned short u16;
typedef unsigned int u32;

__device__ __constant__ int A_FIRST[12]  = {0,3, 0,4, 1,3, 1,4, 2,3, 2,4};
__device__ __constant__ int A_SECOND[12] = {3,0, 4,0, 3,1, 4,1, 3,2, 4,2};

// tanh-form gelu: max |dev| from exact erf-gelu ~0.003 abs; output tol 0.039 -> safe
__device__ __forceinline__ float gelu_f(float x) {
  float n2t = x * fmaf(x * x, -0.0713548163f, -1.5957691216f);  // -2*0.79788456*(x+0.044715x^3)
  return x * __builtin_amdgcn_rcpf(1.0f + __expf(n2t));
}

__device__ __forceinline__ u16 f2bf(float x) {
  u32 u = __builtin_bit_cast(u32, x);
  return (u16)((u + 0x7fffu + ((u >> 16) & 1u)) >> 16);  // RNE
}

__device__ __forceinline__ void load_lds16(const void* g, void* l) {
  __builtin_amdgcn_global_load_lds(
      (const __attribute__((address_space(1))) void*)g,
      (__attribute__((address_space(3))) void*)l,
      16, 0, 0);
}

// ---------------- cast x (fp32 -> bf16), 4 elems/thread ----------------
__global__ void cast_x_kernel(const float* __restrict__ in, __hip_bfloat16* __restrict__ out, int n4) {
  int i = blockIdx.x * blockDim.x + threadIdx.x;
  if (i < n4) {
    float4 v = ((const float4*)in)[i];
    u16* o = (u16*)out + (size_t)i * 4;
    union { u16 s[4]; uint2 d; } pk;
    pk.s[0] = f2bf(v.x); pk.s[1] = f2bf(v.y); pk.s[2] = f2bf(v.z); pk.s[3] = f2bf(v.w);
    *(uint2*)o = pk.d;
  }
}

// ---------------- batched transpose+cast: z=0 -> w, z=1..5 -> a[z-1]; (R,C) fp32 -> (C,R) bf16 ----
__global__ void transpose_cast6(const float* __restrict__ w, const float* __restrict__ a,
                                __hip_bfloat16* __restrict__ wt, __hip_bfloat16* __restrict__ at,
                                int R, int C) {
  __shared__ __hip_bfloat16 tile[32][33];
  int z = blockIdx.z;
  const float* ip = z ? (a + (size_t)(z - 1) * R * C) : w;
  __hip_bfloat16* op = z ? (at + (size_t)(z - 1) * R * C) : wt;
  int c0 = blockIdx.x * 32, r0 = blockIdx.y * 32;
  int tx = threadIdx.x & 31;
  int ty = threadIdx.x >> 5;  // 0..7
#pragma unroll
  for (int s = 0; s < 4; ++s) {
    int rr = ty * 4 + s;
    tile[rr][tx] = __float2bfloat16(ip[(size_t)(r0 + rr) * C + c0 + tx]);
  }
  __syncthreads();
#pragma unroll
  for (int s = 0; s < 4; ++s) {
    int cc = ty * 4 + s;
    op[(size_t)(c0 + cc) * R + r0 + tx] = tile[tx][cc];
  }
}

// ---------------- gate: sel[i*64+b] = argmax of 2 gate logits (2 = tie -> zero output) ----------
__global__ void gate_kernel(const float* __restrict__ x, const float* __restrict__ GW, int* __restrict__ sel) {
  int b = blockIdx.x, i = blockIdx.y;
  int lane = threadIdx.x;
  const float* tok = x + (size_t)(b * TT + i) * DD;
  const float* g = GW + (size_t)i * DD * 2;
  float p0 = 0.f, p1 = 0.f;
  for (int k = lane; k < DD; k += 64) {
    float t = tok[k];
    p0 += t * g[k * 2 + 0];
    p1 += t * g[k * 2 + 1];
  }
#pragma unroll
  for (int o = 32; o; o >>= 1) { p0 += __shfl_xor(p0, o); p1 += __shfl_xor(p1, o); }
  if (lane == 0) sel[i * 64 + b] = (p0 > p1) ? 0 : ((p1 > p0) ? 1 : 2);
}

// ---------------- finalize cls: pick winner combo, sum split-K partials, add bias ----------------
__global__ void finalize_cls(const float* __restrict__ part, const float* __restrict__ A2b,
                             const int* __restrict__ sel, float* __restrict__ out) {
  int t = blockIdx.x * blockDim.x + threadIdx.x;  // 6*64*192
  int d4 = t % 192;
  int b = (t / 192) & 63;
  int cls = t / (192 * 64);
  int s = sel[cls * 64 + b];
  float4 res = make_float4(0.f, 0.f, 0.f, 0.f);
  if (s != 2) {
    int combo = cls * 2 + s;
    const float4* bb = (const float4*)(A2b + (size_t)A_SECOND[combo] * DD);
    res = bb[d4];
#pragma unroll
    for (int z = 0; z < 4; ++z) {
      const float4* p = (const float4*)(part + (((size_t)z * 12 + combo) * 64 + b) * DD);
      float4 v = p[d4];
      res.x += v.x; res.y += v.y; res.z += v.z; res.w += v.w;
    }
  }
  ((float4*)out)[(size_t)(b * TT + cls) * 192 + d4] = res;
}

// ---------------- main MFMA GEMM, BK=64, XOR-swizzled LDS, swapped-operand MFMA ----------------
// mfma(b_frag, a_frag, acc) computes C^T: lane col(lane&15)=m, row(quad*4+reg)=n
// -> per lane 4 consecutive n => packed stores.
// MODE 0: patch layer1: A=xb (patch rows), B=W1t, out=hid bf16 (bias+gelu). BM=128,BN=256.
// MODE 1: patch layer2: A=hid, B=W2t, out=d_out fp32 (bias), patch row remap. 128x128.
// MODE 2: cls layer1  : A=xb tok_i rows, B=A1t[e], out=hcls bf16 (bias+gelu). 64x128.
// MODE 3: cls layer2  : A=hcls[combo], B=A2t[e], split-K z, out=part fp32 raw. 64x128.
template <int BM, int BN, int MODE>
__global__ __launch_bounds__(256, 2)
void gemm_k(const __hip_bfloat16* __restrict__ A,
            const __hip_bfloat16* __restrict__ Bw,
            const float* __restrict__ bias,
            void* __restrict__ Out,
            const int* __restrict__ sel) {
  constexpr int KDIM = (MODE == 0 || MODE == 2) ? DD : HH;
  constexpr int KITERS = (MODE == 3) ? 12 : KDIM / 64;
  constexpr int WAVES_M = (BM == 128) ? 2 : 1;
  constexpr int WAVES_N = 4 / WAVES_M;
  constexpr int MT = BM / (16 * WAVES_M);
  constexpr int NT = BN / (16 * WAVES_N);
  constexpr int CHA = BM / 32;
  constexpr int CHB = BN / 32;

  __shared__ __align__(16) char smem[(BM + BN) * 128];
  char* As = smem;
  char* Bs = smem + BM * 128;

  const int tid = threadIdx.x;
  const int lane = tid & 63;
  const int wave = tid >> 6;
  const int q = lane >> 4;
  const int r = lane & 15;
  const int wave_m = wave / WAVES_N;
  const int wave_n = wave % WAVES_N;

  int m0 = 0, n0, combo = 0, cls_i = 0, zsp = 0;
  size_t k0b = 0;
  const __hip_bfloat16* Bp = Bw;
  const float* biasp = bias;
  if constexpr (MODE == 0) {
    int bx = blockIdx.x;            // 1536 blocks, n-fastest (A-tile LLC reuse)
    m0 = (bx / 12) * BM;
    n0 = (bx % 12) * BN;
  } else if constexpr (MODE == 1) {
    int bx = blockIdx.x;            // 768 blocks, n-fastest
    m0 = (bx / 6) * BM;
    n0 = (bx % 6) * BN;
  } else {
    n0 = blockIdx.x * BN;
    combo = blockIdx.y;
    cls_i = combo >> 1;
    int e = (MODE == 2) ? A_FIRST[combo] : A_SECOND[combo];
    Bp = Bw + (size_t)e * DD * HH;
    if constexpr (MODE == 2) biasp = bias + e * HH;
    if constexpr (MODE == 3) { zsp = blockIdx.z; k0b = (size_t)zsp * 768 * 2; }
  }

  // staging: chunk c = u*256+tid; row = u*32 + (tid>>3); swizzled 16B slot
  const int trow = tid >> 3;
  const int sw = ((tid & 7) ^ (trow & 7)) << 4;
  size_t a_row_off;
  if constexpr (MODE == 0) {
    int m = m0 + trow;
    a_row_off = (size_t)((m >> 8) * TT + 6 + (m & 255)) * DD * 2;  // block never crosses b
  } else if constexpr (MODE == 1) {
    a_row_off = (size_t)(m0 + trow) * HH * 2;
  } else if constexpr (MODE == 2) {
    a_row_off = (size_t)(trow * TT + cls_i) * DD * 2;
  } else {
    a_row_off = (size_t)(combo * 64 + trow) * HH * 2 + k0b;
  }
  const char* gA0 = (const char*)A + a_row_off + sw;
  const char* gB0 = (const char*)Bp + (size_t)(n0 + trow) * KDIM * 2 + k0b + sw;
  constexpr size_t ASTR = (size_t)32 * ((MODE == 0) ? DD : (MODE == 2) ? TT * DD : HH) * 2;
  constexpr size_t BSTR = (size_t)32 * KDIM * 2;
  const int wave_base = (tid & ~63) * 16;

  f32x4 acc[MT][NT];
#pragma unroll
  for (int i_ = 0; i_ < MT; ++i_)
#pragma unroll
    for (int j_ = 0; j_ < NT; ++j_) acc[i_][j_] = (f32x4){0.f, 0.f, 0.f, 0.f};

  const char* a_rd = As + (wave_m * (MT * 16) + r) * 128;
  const char* b_rd = Bs + (wave_n * (NT * 16) + r) * 128;
  const int sa = ((q ^ (r & 7)) << 4);

  for (int kt = 0; kt < KITERS; ++kt) {
#pragma unroll
    for (int u = 0; u < CHA; ++u) load_lds16(gA0 + u * ASTR, As + u * 4096 + wave_base);
#pragma unroll
    for (int u = 0; u < CHB; ++u) load_lds16(gB0 + u * BSTR, Bs + u * 4096 + wave_base);
    gA0 += 128;
    gB0 += 128;
    __syncthreads();
#pragma unroll
    for (int t = 0; t < 2; ++t) {
      const int so = sa ^ (t << 6);
      bf16x8 af[MT], bf[NT];
#pragma unroll
      for (int i_ = 0; i_ < MT; ++i_) af[i_] = *(const bf16x8*)(a_rd + i_ * 2048 + so);
#pragma unroll
      for (int j_ = 0; j_ < NT; ++j_) bf[j_] = *(const bf16x8*)(b_rd + j_ * 2048 + so);
#pragma unroll
      for (int i_ = 0; i_ < MT; ++i_)
#pragma unroll
        for (int j_ = 0; j_ < NT; ++j_)
          acc[i_][j_] = __builtin_amdgcn_mfma_f32_16x16x32_bf16(bf[j_], af[i_], acc[i_][j_], 0, 0, 0);
    }
    __syncthreads();
  }

  // epilogue: swapped C/D -> lane holds m = tile_m + r, n = tile_n + q*4 + [0..4)
#pragma unroll
  for (int i_ = 0; i_ < MT; ++i_) {
    int m_g = m0 + wave_m * (MT * 16) + i_ * 16 + r;
#pragma unroll
    for (int j_ = 0; j_ < NT; ++j_) {
      int nb = n0 + wave_n * (NT * 16) + j_ * 16 + q * 4;
      f32x4 v = acc[i_][j_];
      if constexpr (MODE != 3) {
        f32x4 bb = *(const f32x4*)(biasp + nb);
        v += bb;
      }
      if constexpr (MODE == 0) {
        union { u16 s[4]; uint2 d; } pk;
#pragma unroll
        for (int rg = 0; rg < 4; ++rg) pk.s[rg] = f2bf(gelu_f(v[rg]));
        *(uint2*)((u16*)Out + (size_t)m_g * HH + nb) = pk.d;
      } else if constexpr (MODE == 1) {
        int b = m_g >> 8, p = m_g & 255;
        *(f32x4*)((float*)Out + (size_t)(b * TT + 6 + p) * DD + nb) = v;
      } else if constexpr (MODE == 2) {
        union { u16 s[4]; uint2 d; } pk;
#pragma unroll
        for (int rg = 0; rg < 4; ++rg) pk.s[rg] = f2bf(gelu_f(v[rg]));
        *(uint2*)((u16*)Out + (size_t)(combo * 64 + m_g) * HH + nb) = pk.d;
      } else {
        *(f32x4*)((float*)Out + (((size_t)zsp * 12 + combo) * 64 + m_g) * DD + nb) = v;
      }
    }
  }
}

extern "C" void kernel_launch(void* const* d_in, const int* in_sizes, int n_in,
                              void* d_out, int out_size, void* d_ws, size_t ws_size,
                              hipStream_t stream) {
  const float* x   = (const float*)d_in[0];
  const float* W1  = (const float*)d_in[1];
  const float* b1  = (const float*)d_in[2];
  const float* W2  = (const float*)d_in[3];
  const float* b2  = (const float*)d_in[4];
  const float* A1W = (const float*)d_in[5];
  const float* A1b = (const float*)d_in[6];
  const float* A2W = (const float*)d_in[7];
  const float* A2b = (const float*)d_in[8];
  const float* GW  = (const float*)d_in[9];
  float* out = (float*)d_out;

  char* ws = (char*)d_ws;
  __hip_bfloat16* xb   = (__hip_bfloat16*)(ws + 0);          // 25,755,648
  __hip_bfloat16* W1t  = (__hip_bfloat16*)(ws + 25755648);   //  4,718,592
  __hip_bfloat16* W2t  = (__hip_bfloat16*)(ws + 30474240);   //  4,718,592
  __hip_bfloat16* A1t  = (__hip_bfloat16*)(ws + 35192832);   // 23,592,960
  __hip_bfloat16* A2t  = (__hip_bfloat16*)(ws + 58785792);   // 23,592,960
  __hip_bfloat16* hcls = (__hip_bfloat16*)(ws + 82378752);   //  4,718,592
  int* sel             = (int*)(ws + 87097344);
  __hip_bfloat16* hid  = (__hip_bfloat16*)(ws + 87099136);   // 100,663,296
  float* part          = (float*)(ws + 35192832);            // aliases dead A1t (9.4 MB)

  // preprocessing
  cast_x_kernel<<<12576, 256, 0, stream>>>(x, xb, 3219456);
  transpose_cast6<<<dim3(96, 24, 6), 256, 0, stream>>>(W1, A1W, W1t, A1t, DD, HH);
  transpose_cast6<<<dim3(24, 96, 6), 256, 0, stream>>>(W2, A2W, W2t, A2t, HH, DD);
  gate_kernel<<<dim3(64, 6), 64, 0, stream>>>(x, GW, sel);

  // cls expert path first (frees A1t region for part before cls layer2)
  gemm_k<64, 128, 2><<<dim3(24, 12), 256, 0, stream>>>(xb, A1t, A1b, hcls, nullptr);
  gemm_k<64, 128, 3><<<dim3(6, 12, 4), 256, 0, stream>>>(hcls, A2t, nullptr, part, nullptr);
  finalize_cls<<<288, 256, 0, stream>>>(part, A2b, sel, out);

  // patch MLP
  gemm_k<128, 256, 0><<<1536, 256, 0, stream>>>(xb, W1t, b1, hid, nullptr);
  gemm_k<128, 128, 1><<<768, 256, 0, stream>>>(hid, W2t, b2, out, nullptr);
}

// Round 4
// 392.008 us; speedup vs baseline: 1.1441x; 1.1441x over previous
//
#include <hip/hip_runtime.h>
#include <hip/hip_bf16.h>

#define DD 768
#define HH 3072
#define BB 64
#define TT 262   // NCLS + P tokens per batch

typedef __bf16 bf16x8 __attribute__((ext_vector_type(8)));
typedef float f32x4 __attribute__((ext_vector_type(4)));
typedef unsigned short u16;
typedef unsigned int u32;

__device__ __constant__ int A_FIRST[12]  = {0,3, 0,4, 1,3, 1,4, 2,3, 2,4};
__device__ __constant__ int A_SECOND[12] = {3,0, 4,0, 3,1, 4,1, 3,2, 4,2};

// tanh-form gelu: max |dev| from exact erf-gelu ~0.003 abs; output tol 0.039 -> safe
__device__ __forceinline__ float gelu_f(float x) {
  float n2t = x * fmaf(x * x, -0.0713548163f, -1.5957691216f);
  return x * __builtin_amdgcn_rcpf(1.0f + __expf(n2t));
}

__device__ __forceinline__ u16 f2bf(float x) {
  u32 u = __builtin_bit_cast(u32, x);
  return (u16)((u + 0x7fffu + ((u >> 16) & 1u)) >> 16);  // RNE
}

__device__ __forceinline__ void load_lds16(const void* g, void* l) {
  __builtin_amdgcn_global_load_lds(
      (const __attribute__((address_space(1))) void*)g,
      (__attribute__((address_space(3))) void*)l,
      16, 0, 0);
}

// =================== fused preprocessing: cast_x | transpose x2 | gate ===================
// blocks [0,12576): cast x fp32->bf16 (4 elems/thread)
// blocks [12576,26400): transpose-cast (768,3072)->(3072,768), z=0:W1 z=1..5:A1W
// blocks [26400,40224): transpose-cast (3072,768)->(768,3072), z=0:W2 z=1..5:A2W
// blocks [40224,40320): gate, 4 waves/block, one (b,cls) unit per wave
__global__ __launch_bounds__(256)
void preproc(const float* __restrict__ x,
             const float* __restrict__ W1, const float* __restrict__ A1W,
             const float* __restrict__ W2, const float* __restrict__ A2W,
             const float* __restrict__ GW,
             __hip_bfloat16* __restrict__ xb,
             __hip_bfloat16* __restrict__ W1t, __hip_bfloat16* __restrict__ A1t,
             __hip_bfloat16* __restrict__ W2t, __hip_bfloat16* __restrict__ A2t,
             int* __restrict__ sel) {
  __shared__ __hip_bfloat16 tile[32][33];
  const int bx = blockIdx.x;
  const int tid = threadIdx.x;
  if (bx < 12576) {
    int i = bx * 256 + tid;  // 12576*256 == 3219456 exactly
    float4 v = ((const float4*)x)[i];
    union { u16 s[4]; uint2 d; } pk;
    pk.s[0] = f2bf(v.x); pk.s[1] = f2bf(v.y); pk.s[2] = f2bf(v.z); pk.s[3] = f2bf(v.w);
    *(uint2*)((u16*)xb + (size_t)i * 4) = pk.d;
  } else if (bx < 40224) {
    int R, C;
    const float* ip;
    __hip_bfloat16* op;
    int t;
    if (bx < 26400) {
      t = bx - 12576; R = DD; C = HH;
      int z = t / 2304; t %= 2304;
      ip = z ? (A1W + (size_t)(z - 1) * DD * HH) : W1;
      op = z ? (A1t + (size_t)(z - 1) * DD * HH) : W1t;
    } else {
      t = bx - 26400; R = HH; C = DD;
      int z = t / 2304; t %= 2304;
      ip = z ? (A2W + (size_t)(z - 1) * DD * HH) : W2;
      op = z ? (A2t + (size_t)(z - 1) * DD * HH) : W2t;
    }
    int ctiles = C >> 5;
    int c0 = (t % ctiles) * 32, r0 = (t / ctiles) * 32;
    int tx = tid & 31, ty = tid >> 5;
#pragma unroll
    for (int s = 0; s < 4; ++s) {
      int rr = ty * 4 + s;
      tile[rr][tx] = __float2bfloat16(ip[(size_t)(r0 + rr) * C + c0 + tx]);
    }
    __syncthreads();
#pragma unroll
    for (int s = 0; s < 4; ++s) {
      int cc = ty * 4 + s;
      op[(size_t)(c0 + cc) * R + r0 + tx] = tile[tx][cc];
    }
  } else {
    int unit = (bx - 40224) * 4 + (tid >> 6);  // 384 units = 64 b x 6 cls
    int lane = tid & 63;
    int b = unit & 63, i = unit >> 6;
    const float* tok = x + (size_t)(b * TT + i) * DD;
    const float* g = GW + (size_t)i * DD * 2;
    float p0 = 0.f, p1 = 0.f;
    for (int k = lane; k < DD; k += 64) {
      float tv = tok[k];
      p0 += tv * g[k * 2 + 0];
      p1 += tv * g[k * 2 + 1];
    }
#pragma unroll
    for (int o = 32; o; o >>= 1) { p0 += __shfl_xor(p0, o); p1 += __shfl_xor(p1, o); }
    if (lane == 0) sel[i * 64 + b] = (p0 > p1) ? 0 : ((p1 > p0) ? 1 : 2);
  }
}

// =================== MFMA GEMM body, BK=64, XOR-swizzled LDS, swapped-operand ===================
// mfma(b_frag, a_frag, acc): lane holds m = r, n = q*4+[0..4) -> packed stores.
// MODE 0: patch layer1: A=xb patches, B=W1t, out=hid bf16 (bias+gelu). 128x256, supertiled.
// MODE 1: patch layer2: A=hid, B=W2t, out=d_out fp32 (bias), row remap. 128x128, supertiled.
// MODE 2: cls layer1  : A=xb cls rows, B=A1t[e], out=hcls bf16 (bias+gelu). 64x128.
// MODE 3: cls layer2  : A=hcls[combo], B=A2t[e], full K, masked+biased write to out. 64x128.
template <int BM, int BN, int MODE>
__device__ __forceinline__
void gemm_body(char* __restrict__ smem, int bx,
               const __hip_bfloat16* __restrict__ A,
               const __hip_bfloat16* __restrict__ Bw,
               const float* __restrict__ bias,
               void* __restrict__ Out,
               const int* __restrict__ sel) {
  constexpr int KDIM = (MODE == 0 || MODE == 2) ? DD : HH;
  constexpr int KITERS = KDIM / 64;
  constexpr int WAVES_M = (BM == 128) ? 2 : 1;
  constexpr int WAVES_N = 4 / WAVES_M;
  constexpr int MT = BM / (16 * WAVES_M);
  constexpr int NT = BN / (16 * WAVES_N);
  constexpr int CHA = BM / 32;
  constexpr int CHB = BN / 32;

  char* As = smem;
  char* Bs = smem + BM * 128;

  const int tid = threadIdx.x;
  const int lane = tid & 63;
  const int wave = tid >> 6;
  const int q = lane >> 4;
  const int r = lane & 15;
  const int wave_m = wave / WAVES_N;
  const int wave_n = wave % WAVES_N;

  int m0 = 0, n0, combo = 0, cls_i = 0;
  const __hip_bfloat16* Bp = Bw;
  const float* biasp = bias;
  if constexpr (MODE == 0) {
    // supertile: chunks of 16 m-blocks; within chunk m-fastest (B-tile reuse), 12 n-cols
    int chunk = bx / 192, local = bx % 192;
    int nb = local / 16, mloc = local % 16;
    m0 = (chunk * 16 + mloc) * BM;
    n0 = nb * BN;
  } else if constexpr (MODE == 1) {
    int chunk = bx / 96, local = bx % 96;
    int nb = local / 16, mloc = local % 16;
    m0 = (chunk * 16 + mloc) * BM;
    n0 = nb * BN;
  } else if constexpr (MODE == 2) {
    n0 = (bx % 24) * BN;
    combo = bx / 24;
    cls_i = combo >> 1;
    int e = A_FIRST[combo];
    Bp = Bw + (size_t)e * DD * HH;
    biasp = bias + e * HH;
  } else {
    n0 = (bx % 6) * BN;
    combo = bx / 6;
    cls_i = combo >> 1;
    int e = A_SECOND[combo];
    Bp = Bw + (size_t)e * DD * HH;
    biasp = bias + e * DD;
  }

  // staging: chunk c = u*256+tid; row = u*32 + (tid>>3); swizzled 16B slot
  const int trow = tid >> 3;
  const int sw = ((tid & 7) ^ (trow & 7)) << 4;
  size_t a_row_off;
  if constexpr (MODE == 0) {
    int m = m0 + trow;
    a_row_off = (size_t)((m >> 8) * TT + 6 + (m & 255)) * DD * 2;
  } else if constexpr (MODE == 1) {
    a_row_off = (size_t)(m0 + trow) * HH * 2;
  } else if constexpr (MODE == 2) {
    a_row_off = (size_t)(trow * TT + cls_i) * DD * 2;
  } else {
    a_row_off = (size_t)(combo * 64 + trow) * HH * 2;
  }
  const char* gA0 = (const char*)A + a_row_off + sw;
  const char* gB0 = (const char*)Bp + (size_t)(n0 + trow) * KDIM * 2 + sw;
  constexpr size_t ASTR = (size_t)32 * ((MODE == 0) ? DD : (MODE == 2) ? TT * DD : HH) * 2;
  constexpr size_t BSTR = (size_t)32 * KDIM * 2;
  const int wave_base = (tid & ~63) * 16;

  f32x4 acc[MT][NT];
#pragma unroll
  for (int i_ = 0; i_ < MT; ++i_)
#pragma unroll
    for (int j_ = 0; j_ < NT; ++j_) acc[i_][j_] = (f32x4){0.f, 0.f, 0.f, 0.f};

  const char* a_rd = As + (wave_m * (MT * 16) + r) * 128;
  const char* b_rd = Bs + (wave_n * (NT * 16) + r) * 128;
  const int sa = ((q ^ (r & 7)) << 4);

  for (int kt = 0; kt < KITERS; ++kt) {
#pragma unroll
    for (int u = 0; u < CHA; ++u) load_lds16(gA0 + u * ASTR, As + u * 4096 + wave_base);
#pragma unroll
    for (int u = 0; u < CHB; ++u) load_lds16(gB0 + u * BSTR, Bs + u * 4096 + wave_base);
    gA0 += 128;
    gB0 += 128;
    __syncthreads();
#pragma unroll
    for (int t = 0; t < 2; ++t) {
      const int so = sa ^ (t << 6);
      bf16x8 af[MT], bf[NT];
#pragma unroll
      for (int i_ = 0; i_ < MT; ++i_) af[i_] = *(const bf16x8*)(a_rd + i_ * 2048 + so);
#pragma unroll
      for (int j_ = 0; j_ < NT; ++j_) bf[j_] = *(const bf16x8*)(b_rd + j_ * 2048 + so);
#pragma unroll
      for (int i_ = 0; i_ < MT; ++i_)
#pragma unroll
        for (int j_ = 0; j_ < NT; ++j_)
          acc[i_][j_] = __builtin_amdgcn_mfma_f32_16x16x32_bf16(bf[j_], af[i_], acc[i_][j_], 0, 0, 0);
    }
    __syncthreads();
  }

  // epilogue: lane holds m = tile_m + r, n = tile_n + q*4 + [0..4)
#pragma unroll
  for (int i_ = 0; i_ < MT; ++i_) {
    int m_g = m0 + wave_m * (MT * 16) + i_ * 16 + r;
#pragma unroll
    for (int j_ = 0; j_ < NT; ++j_) {
      int nb = n0 + wave_n * (NT * 16) + j_ * 16 + q * 4;
      f32x4 v = acc[i_][j_];
      f32x4 bb = *(const f32x4*)(biasp + nb);
      v += bb;
      if constexpr (MODE == 0) {
        union { u16 s[4]; uint2 d; } pk;
#pragma unroll
        for (int rg = 0; rg < 4; ++rg) pk.s[rg] = f2bf(gelu_f(v[rg]));
        *(uint2*)((u16*)Out + (size_t)m_g * HH + nb) = pk.d;
      } else if constexpr (MODE == 1) {
        int b = m_g >> 8, p = m_g & 255;
        *(f32x4*)((float*)Out + (size_t)(b * TT + 6 + p) * DD + nb) = v;
      } else if constexpr (MODE == 2) {
        union { u16 s[4]; uint2 d; } pk;
#pragma unroll
        for (int rg = 0; rg < 4; ++rg) pk.s[rg] = f2bf(gelu_f(v[rg]));
        *(uint2*)((u16*)Out + (size_t)(combo * 64 + m_g) * HH + nb) = pk.d;
      } else {
        int s = sel[cls_i * 64 + m_g];
        int j = combo & 1;
        float* dst = (float*)Out + (size_t)(m_g * TT + cls_i) * DD + nb;
        if (s == j) {
          *(f32x4*)dst = v;
        } else if (j == 0 && s == 2) {
          *(f32x4*)dst = (f32x4){0.f, 0.f, 0.f, 0.f};
        }
      }
    }
  }
}

// mega1: blocks [0,1536) patch layer1 (128x256); [1536,1824) cls layer1 (64x128)
__global__ __launch_bounds__(256, 2)
void mega1(const __hip_bfloat16* __restrict__ xb, const __hip_bfloat16* __restrict__ W1t,
           const float* __restrict__ b1, __hip_bfloat16* __restrict__ hid,
           const __hip_bfloat16* __restrict__ A1t, const float* __restrict__ A1b,
           __hip_bfloat16* __restrict__ hcls) {
  __shared__ __align__(16) char smem[(128 + 256) * 128];
  int bx = blockIdx.x;
  if (bx < 1536) gemm_body<128, 256, 0>(smem, bx, xb, W1t, b1, hid, nullptr);
  else           gemm_body<64, 128, 2>(smem, bx - 1536, xb, A1t, A1b, hcls, nullptr);
}

// mega2: blocks [0,768) patch layer2 (128x128); [768,840) cls layer2 (64x128, full K)
__global__ __launch_bounds__(256, 2)
void mega2(const __hip_bfloat16* __restrict__ hid, const __hip_bfloat16* __restrict__ W2t,
           const float* __restrict__ b2, float* __restrict__ out,
           const __hip_bfloat16* __restrict__ hcls, const __hip_bfloat16* __restrict__ A2t,
           const float* __restrict__ A2b, const int* __restrict__ sel) {
  __shared__ __align__(16) char smem[(128 + 128) * 128];
  int bx = blockIdx.x;
  if (bx < 768) gemm_body<128, 128, 1>(smem, bx, hid, W2t, b2, out, nullptr);
  else          gemm_body<64, 128, 3>(smem, bx - 768, hcls, A2t, A2b, out, sel);
}

extern "C" void kernel_launch(void* const* d_in, const int* in_sizes, int n_in,
                              void* d_out, int out_size, void* d_ws, size_t ws_size,
                              hipStream_t stream) {
  const float* x   = (const float*)d_in[0];
  const float* W1  = (const float*)d_in[1];
  const float* b1  = (const float*)d_in[2];
  const float* W2  = (const float*)d_in[3];
  const float* b2  = (const float*)d_in[4];
  const float* A1W = (const float*)d_in[5];
  const float* A1b = (const float*)d_in[6];
  const float* A2W = (const float*)d_in[7];
  const float* A2b = (const float*)d_in[8];
  const float* GW  = (const float*)d_in[9];
  float* out = (float*)d_out;

  char* ws = (char*)d_ws;
  __hip_bfloat16* xb   = (__hip_bfloat16*)(ws + 0);          // 25,755,648
  __hip_bfloat16* W1t  = (__hip_bfloat16*)(ws + 25755648);   //  4,718,592
  __hip_bfloat16* W2t  = (__hip_bfloat16*)(ws + 30474240);   //  4,718,592
  __hip_bfloat16* A1t  = (__hip_bfloat16*)(ws + 35192832);   // 23,592,960
  __hip_bfloat16* A2t  = (__hip_bfloat16*)(ws + 58785792);   // 23,592,960
  __hip_bfloat16* hcls = (__hip_bfloat16*)(ws + 82378752);   //  4,718,592
  int* sel             = (int*)(ws + 87097344);
  __hip_bfloat16* hid  = (__hip_bfloat16*)(ws + 87099136);   // 100,663,296

  preproc<<<40320, 256, 0, stream>>>(x, W1, A1W, W2, A2W, GW, xb, W1t, A1t, W2t, A2t, sel);
  mega1<<<1824, 256, 0, stream>>>(xb, W1t, b1, hid, A1t, A1b, hcls);
  mega2<<<840, 256, 0, stream>>>(hid, W2t, b2, out, hcls, A2t, A2b, sel);
}